// Round 2
// baseline (276.816 us; speedup 1.0000x reference)
//
#include <hip/hip_runtime.h>

// out = x + softmax((x@Wq) @ (rs@Wk)^T) @ (rs@Wv)
// B=4 T=8 N=2048 C=D=128 M=2048. fp32 in/out.
// Precision scheme: hi/lo bf16 split (Markidis) for Q,K projection and QK^T;
// single bf16 for P and V. Keeps logit error ~1e-3 (fp32-like).

#define Bn 4
#define Tn 8
#define Nn 2048
#define Cn 128
#define Mn 2048

typedef __attribute__((ext_vector_type(4))) float f32x4;
typedef __attribute__((ext_vector_type(8))) short bf16x8;

__device__ __forceinline__ unsigned short f2bf(float f) {
  unsigned int u = __float_as_uint(f);
  u += 0x7fffu + ((u >> 16) & 1u);
  return (unsigned short)(u >> 16);
}
__device__ __forceinline__ float bf2f(unsigned short h) {
  return __uint_as_float(((unsigned int)h) << 16);
}
__device__ __forceinline__ unsigned short f2bf_lo(float v) {
  unsigned short h = f2bf(v);
  return f2bf(v - bf2f(h));
}

// Swizzled LDS read of 8 bf16 (16B). byte ^= (row&7)<<4 (bank-conflict fix).
__device__ __forceinline__ bf16x8 lds_read8(const unsigned char* base, int row,
                                            int rowBytes, int colByte) {
  int byte = row * rowBytes + (colByte ^ ((row & 7) << 4));
  return *(const bf16x8*)(base + byte);
}

// ---------------------------------------------------------------------------
// Kernel A: K_hi/K_lo = split(rs@Wk) [b][m][d]; V^T = bf16(rs@Wv) [b][d][m]
// grid: B*(M/64)=128 blocks, 256 threads. LDS 64KB.
// ---------------------------------------------------------------------------
__global__ __launch_bounds__(256) void proj_kv_kernel(
    const float* __restrict__ rs, const float* __restrict__ Wk,
    const float* __restrict__ Wv, unsigned short* __restrict__ kh_ws,
    unsigned short* __restrict__ kl_ws, unsigned short* __restrict__ vt_ws) {
  __shared__ unsigned char smem[64 * 1024];
  unsigned char* rsh = smem;              // [64][128] bf16 swz (16KB)
  unsigned char* rsl = smem + 16 * 1024;  // [64][128] bf16 swz (16KB)
  unsigned char* wt = smem + 32 * 1024;   // [128][128] bf16 swz, W^T (32KB)

  const int bid = blockIdx.x;
  const int b = bid >> 5;
  const int m0 = (bid & 31) << 6;
  const int tid = threadIdx.x;
  const int wv = tid >> 6, lane = tid & 63;

  // stage rs tile hi/lo: 64x128 f32. 2048 float4 / 256 thr = 8 each.
  {
    const float4* g = (const float4*)(rs + ((size_t)b * Mn + m0) * Cn);
#pragma unroll
    for (int i = 0; i < 8; ++i) {
      int f = tid + i * 256;
      int row = f >> 5, c4 = f & 31;
      float4 v = g[f];
      int byte = row * 256 + ((c4 * 8) ^ ((row & 7) << 4));
      ushort4 h = make_ushort4(f2bf(v.x), f2bf(v.y), f2bf(v.z), f2bf(v.w));
      *(ushort4*)(rsh + byte) = h;
      *(ushort4*)(rsl + byte) =
          make_ushort4(f2bf(v.x - bf2f(h.x)), f2bf(v.y - bf2f(h.y)),
                       f2bf(v.z - bf2f(h.z)), f2bf(v.w - bf2f(h.w)));
    }
  }

  // stage W^T (hi or lo of W[c][d] -> wt[d][c])
#define STAGE_WT(Wp, LO)                                                      \
  {                                                                           \
    const float4* g = (const float4*)(Wp);                                    \
    _Pragma("unroll") for (int i = 0; i < 16; ++i) {                          \
      int f = tid + i * 256;                                                  \
      int c = f >> 5, d0 = (f & 31) * 4;                                      \
      float4 v = g[f];                                                        \
      float vv[4] = {v.x, v.y, v.z, v.w};                                     \
      _Pragma("unroll") for (int j = 0; j < 4; ++j) {                         \
        int row = d0 + j;                                                     \
        int byte = row * 256 + ((c * 2) ^ ((row & 7) << 4));                  \
        *(unsigned short*)(wt + byte) = (LO) ? f2bf_lo(vv[j]) : f2bf(vv[j]);  \
      }                                                                       \
    }                                                                         \
  }

  STAGE_WT(Wk, false);
  __syncthreads();

  const int arow = wv * 16 + (lane & 15);
  bf16x8 ah[4], al[4];
#pragma unroll
  for (int ks = 0; ks < 4; ++ks) {
    int cb = ((lane >> 4) * 8 + ks * 32) * 2;
    ah[ks] = lds_read8(rsh, arow, 256, cb);
    al[ks] = lds_read8(rsl, arow, 256, cb);
  }

  f32x4 acc[8];
#pragma unroll
  for (int df = 0; df < 8; ++df) acc[df] = (f32x4)(0.0f);
  // rs_hi*Wk_hi + rs_lo*Wk_hi
#pragma unroll
  for (int ks = 0; ks < 4; ++ks)
#pragma unroll
    for (int df = 0; df < 8; ++df) {
      bf16x8 bf = lds_read8(wt, df * 16 + (lane & 15), 256,
                            ((lane >> 4) * 8 + ks * 32) * 2);
      acc[df] = __builtin_amdgcn_mfma_f32_16x16x32_bf16(ah[ks], bf, acc[df], 0, 0, 0);
      acc[df] = __builtin_amdgcn_mfma_f32_16x16x32_bf16(al[ks], bf, acc[df], 0, 0, 0);
    }
  __syncthreads();
  STAGE_WT(Wk, true);
  __syncthreads();
  // + rs_hi*Wk_lo
#pragma unroll
  for (int ks = 0; ks < 4; ++ks)
#pragma unroll
    for (int df = 0; df < 8; ++df) {
      bf16x8 bf = lds_read8(wt, df * 16 + (lane & 15), 256,
                            ((lane >> 4) * 8 + ks * 32) * 2);
      acc[df] = __builtin_amdgcn_mfma_f32_16x16x32_bf16(ah[ks], bf, acc[df], 0, 0, 0);
    }
  {
    unsigned short* khb = kh_ws + (size_t)b * Mn * Cn;
    unsigned short* klb = kl_ws + (size_t)b * Mn * Cn;
#pragma unroll
    for (int df = 0; df < 8; ++df)
#pragma unroll
      for (int r = 0; r < 4; ++r) {
        int row = wv * 16 + (lane >> 4) * 4 + r;
        int dcol = df * 16 + (lane & 15);
        float v = acc[df][r];
        unsigned short h = f2bf(v);
        khb[(size_t)(m0 + row) * Cn + dcol] = h;
        klb[(size_t)(m0 + row) * Cn + dcol] = f2bf(v - bf2f(h));
      }
  }
  __syncthreads();

  // ---- V ----
  STAGE_WT(Wv, false);
  __syncthreads();
#pragma unroll
  for (int df = 0; df < 8; ++df) acc[df] = (f32x4)(0.0f);
#pragma unroll
  for (int ks = 0; ks < 4; ++ks)
#pragma unroll
    for (int df = 0; df < 8; ++df) {
      bf16x8 bf = lds_read8(wt, df * 16 + (lane & 15), 256,
                            ((lane >> 4) * 8 + ks * 32) * 2);
      acc[df] = __builtin_amdgcn_mfma_f32_16x16x32_bf16(ah[ks], bf, acc[df], 0, 0, 0);
      acc[df] = __builtin_amdgcn_mfma_f32_16x16x32_bf16(al[ks], bf, acc[df], 0, 0, 0);
    }
  __syncthreads();
  STAGE_WT(Wv, true);
  __syncthreads();
#pragma unroll
  for (int ks = 0; ks < 4; ++ks)
#pragma unroll
    for (int df = 0; df < 8; ++df) {
      bf16x8 bf = lds_read8(wt, df * 16 + (lane & 15), 256,
                            ((lane >> 4) * 8 + ks * 32) * 2);
      acc[df] = __builtin_amdgcn_mfma_f32_16x16x32_bf16(ah[ks], bf, acc[df], 0, 0, 0);
    }
  {
    unsigned short* vb = vt_ws + (size_t)b * Cn * Mn;
#pragma unroll
    for (int df = 0; df < 8; ++df)
#pragma unroll
      for (int r = 0; r < 4; ++r) {
        int row = wv * 16 + (lane >> 4) * 4 + r;
        int dcol = df * 16 + (lane & 15);
        vb[(size_t)dcol * Mn + (m0 + row)] = f2bf(acc[df][r]);
      }
  }
#undef STAGE_WT
}

// ---------------------------------------------------------------------------
// Kernel B: fused flash attention. grid: B*T*(N/128)=512 blocks, 512 thr.
// LDS 64KB. Prologue (3-pass restage): xa=smem[0,32K) xb buffer, wb=[32K,64K).
// Main loop: k_hi@0 (16K), k_lo@16K, vt@32K (16K), p@48K (per-wave 2KB).
// ---------------------------------------------------------------------------
__global__ __launch_bounds__(512, 4) void attn_kernel(
    const float* __restrict__ x, const float* __restrict__ Wq,
    const unsigned short* __restrict__ kh_ws,
    const unsigned short* __restrict__ kl_ws,
    const unsigned short* __restrict__ vt_ws, float* __restrict__ out) {
  __shared__ unsigned char smem[64 * 1024];
  unsigned char* xa = smem;               // prologue x buffer [128][128] bf16
  unsigned char* wb = smem + 32 * 1024;   // prologue W^T buffer
  unsigned char* k_hi = smem;             // main
  unsigned char* k_lo = smem + 16 * 1024;
  unsigned char* vt_lds = smem + 32 * 1024;

  const int bid = blockIdx.x;
  const int NQT = Nn / 128;  // 16
  const int b = bid / (Tn * NQT);
  const int t = (bid / NQT) % Tn;
  const int n0 = (bid % NQT) * 128;
  const int tid = threadIdx.x;
  const int wv = tid >> 6, lane = tid & 63;
  unsigned char* p_lds = smem + 48 * 1024 + wv * 2048;  // per-wave [16][64]

  const float* xb_g = x + (((size_t)b * Tn + t) * Nn + n0) * Cn;

#define STAGE_X(LO)                                                           \
  {                                                                           \
    const float4* g = (const float4*)xb_g;                                    \
    _Pragma("unroll") for (int i = 0; i < 8; ++i) {                           \
      int f = tid + i * 512;                                                  \
      int row = f >> 5, c4 = f & 31;                                          \
      float4 v = g[f];                                                        \
      int byte = row * 256 + ((c4 * 8) ^ ((row & 7) << 4));                   \
      if (LO)                                                                 \
        *(ushort4*)(xa + byte) = make_ushort4(f2bf_lo(v.x), f2bf_lo(v.y),     \
                                              f2bf_lo(v.z), f2bf_lo(v.w));    \
      else                                                                    \
        *(ushort4*)(xa + byte) =                                              \
            make_ushort4(f2bf(v.x), f2bf(v.y), f2bf(v.z), f2bf(v.w));         \
    }                                                                         \
  }
#define STAGE_WQ(LO)                                                          \
  {                                                                           \
    const float4* g = (const float4*)Wq;                                      \
    _Pragma("unroll") for (int i = 0; i < 8; ++i) {                           \
      int f = tid + i * 512;                                                  \
      int c = f >> 5, d0 = (f & 31) * 4;                                      \
      float4 v = g[f];                                                        \
      float vv[4] = {v.x, v.y, v.z, v.w};                                     \
      _Pragma("unroll") for (int j = 0; j < 4; ++j) {                         \
        int row = d0 + j;                                                     \
        int byte = row * 256 + ((c * 2) ^ ((row & 7) << 4));                  \
        *(unsigned short*)(wb + byte) = (LO) ? f2bf_lo(vv[j]) : f2bf(vv[j]);  \
      }                                                                       \
    }                                                                         \
  }

  const int arow = wv * 16 + (lane & 15);
  f32x4 qacc[8];
#pragma unroll
  for (int df = 0; df < 8; ++df) qacc[df] = (f32x4)(0.0f);

  // pass 1: x_hi * wq_hi
  STAGE_X(false);
  STAGE_WQ(false);
  __syncthreads();
  bf16x8 xfrag[4];
#pragma unroll
  for (int ks = 0; ks < 4; ++ks)
    xfrag[ks] = lds_read8(xa, arow, 256, ((lane >> 4) * 8 + ks * 32) * 2);
#pragma unroll
  for (int ks = 0; ks < 4; ++ks)
#pragma unroll
    for (int df = 0; df < 8; ++df) {
      bf16x8 bf = lds_read8(wb, df * 16 + (lane & 15), 256,
                            ((lane >> 4) * 8 + ks * 32) * 2);
      qacc[df] = __builtin_amdgcn_mfma_f32_16x16x32_bf16(xfrag[ks], bf, qacc[df], 0, 0, 0);
    }
  __syncthreads();
  // pass 2: x_hi * wq_lo
  STAGE_WQ(true);
  __syncthreads();
#pragma unroll
  for (int ks = 0; ks < 4; ++ks)
#pragma unroll
    for (int df = 0; df < 8; ++df) {
      bf16x8 bf = lds_read8(wb, df * 16 + (lane & 15), 256,
                            ((lane >> 4) * 8 + ks * 32) * 2);
      qacc[df] = __builtin_amdgcn_mfma_f32_16x16x32_bf16(xfrag[ks], bf, qacc[df], 0, 0, 0);
    }
  __syncthreads();
  // pass 3: x_lo * wq_hi
  STAGE_X(true);
  STAGE_WQ(false);
  __syncthreads();
#pragma unroll
  for (int ks = 0; ks < 4; ++ks)
    xfrag[ks] = lds_read8(xa, arow, 256, ((lane >> 4) * 8 + ks * 32) * 2);
#pragma unroll
  for (int ks = 0; ks < 4; ++ks)
#pragma unroll
    for (int df = 0; df < 8; ++df) {
      bf16x8 bf = lds_read8(wb, df * 16 + (lane & 15), 256,
                            ((lane >> 4) * 8 + ks * 32) * 2);
      qacc[df] = __builtin_amdgcn_mfma_f32_16x16x32_bf16(xfrag[ks], bf, qacc[df], 0, 0, 0);
    }
  __syncthreads();

  // split q -> hi/lo bf16, round-trip through LDS to A-fragment layout
  // (wave-local rows; in-wave LDS ordering makes this race-free)
#pragma unroll
  for (int df = 0; df < 8; ++df)
#pragma unroll
    for (int r = 0; r < 4; ++r) {
      int row = wv * 16 + (lane >> 4) * 4 + r;
      int col = df * 16 + (lane & 15);
      int byte = row * 256 + ((col * 2) ^ ((row & 7) << 4));
      float v = qacc[df][r];
      unsigned short h = f2bf(v);
      *(unsigned short*)(xa + byte) = h;
      *(unsigned short*)(wb + byte) = f2bf(v - bf2f(h));
    }
  bf16x8 qh[4], ql[4];
#pragma unroll
  for (int ks = 0; ks < 4; ++ks) {
    int cb = ((lane >> 4) * 8 + ks * 32) * 2;
    qh[ks] = lds_read8(xa, arow, 256, cb);
    ql[ks] = lds_read8(wb, arow, 256, cb);
  }
  __syncthreads();  // all waves done with xa/wb before k/vt staging

  // ---- flash loop over M in tiles of 64 ----
  f32x4 o[8];
#pragma unroll
  for (int df = 0; df < 8; ++df) o[df] = (f32x4)(0.0f);
  float mrow[4] = {-INFINITY, -INFINITY, -INFINITY, -INFINITY};
  float lrow[4] = {0.f, 0.f, 0.f, 0.f};

  const unsigned short* khg = kh_ws + (size_t)b * Mn * Cn;
  const unsigned short* klg = kl_ws + (size_t)b * Mn * Cn;
  const unsigned short* vtg = vt_ws + (size_t)b * Cn * Mn;

  for (int kt = 0; kt < Mn / 64; ++kt) {
    {
      const uint4* gh = (const uint4*)(khg + (size_t)kt * 64 * Cn);
      const uint4* gl = (const uint4*)(klg + (size_t)kt * 64 * Cn);
#pragma unroll
      for (int i = 0; i < 2; ++i) {
        int f = tid + i * 512;
        int row = f >> 4, c8 = f & 15;
        int byte = row * 256 + ((c8 * 16) ^ ((row & 7) << 4));
        *(uint4*)(k_hi + byte) = gh[f];
        *(uint4*)(k_lo + byte) = gl[f];
      }
#pragma unroll
      for (int i = 0; i < 2; ++i) {
        int f = tid + i * 512;
        int d = f >> 3, c8 = f & 7;
        uint4 v = *(const uint4*)(vtg + (size_t)d * Mn + kt * 64 + c8 * 8);
        int byte = d * 128 + ((c8 * 16) ^ ((d & 7) << 4));
        *(uint4*)(vt_lds + byte) = v;
      }
    }
    __syncthreads();

    // S = q@k^T, 3-term split: qh*kh + qh*kl + ql*kh
    f32x4 s[4];
#pragma unroll
    for (int jf = 0; jf < 4; ++jf) s[jf] = (f32x4)(0.0f);
#pragma unroll
    for (int ks = 0; ks < 4; ++ks)
#pragma unroll
      for (int jf = 0; jf < 4; ++jf) {
        int row = jf * 16 + (lane & 15);
        int cb = ((lane >> 4) * 8 + ks * 32) * 2;
        bf16x8 kfh = lds_read8(k_hi, row, 256, cb);
        bf16x8 kfl = lds_read8(k_lo, row, 256, cb);
        s[jf] = __builtin_amdgcn_mfma_f32_16x16x32_bf16(qh[ks], kfh, s[jf], 0, 0, 0);
        s[jf] = __builtin_amdgcn_mfma_f32_16x16x32_bf16(qh[ks], kfl, s[jf], 0, 0, 0);
        s[jf] = __builtin_amdgcn_mfma_f32_16x16x32_bf16(ql[ks], kfh, s[jf], 0, 0, 0);
      }

    // online softmax (16-lane groups hold a row)
    float scl[4];
#pragma unroll
    for (int r = 0; r < 4; ++r) {
      float tm = fmaxf(fmaxf(s[0][r], s[1][r]), fmaxf(s[2][r], s[3][r]));
#pragma unroll
      for (int off = 1; off < 16; off <<= 1)
        tm = fmaxf(tm, __shfl_xor(tm, off, 16));
      float mn = fmaxf(mrow[r], tm);
      scl[r] = __expf(mrow[r] - mn);
      float rsum = 0.f;
#pragma unroll
      for (int jf = 0; jf < 4; ++jf) {
        float p = __expf(s[jf][r] - mn);
        s[jf][r] = p;
        rsum += p;
      }
#pragma unroll
      for (int off = 1; off < 16; off <<= 1) rsum += __shfl_xor(rsum, off, 16);
      lrow[r] = lrow[r] * scl[r] + rsum;
      mrow[r] = mn;
    }
#pragma unroll
    for (int df = 0; df < 8; ++df)
#pragma unroll
      for (int r = 0; r < 4; ++r) o[df][r] *= scl[r];

    // P -> per-wave LDS (bf16), re-read as A-fragments
#pragma unroll
    for (int jf = 0; jf < 4; ++jf)
#pragma unroll
      for (int r = 0; r < 4; ++r) {
        int prow = (lane >> 4) * 4 + r;
        int pcol = jf * 16 + (lane & 15);
        int byte = prow * 128 + ((pcol * 2) ^ ((prow & 7) << 4));
        *(unsigned short*)(p_lds + byte) = f2bf(s[jf][r]);
      }
    bf16x8 pa[2];
#pragma unroll
    for (int ks = 0; ks < 2; ++ks)
      pa[ks] = lds_read8(p_lds, lane & 15, 128, ((lane >> 4) * 8 + ks * 32) * 2);

    // O += P @ V
#pragma unroll
    for (int ks = 0; ks < 2; ++ks)
#pragma unroll
      for (int df = 0; df < 8; ++df) {
        bf16x8 vf = lds_read8(vt_lds, df * 16 + (lane & 15), 128,
                              ((lane >> 4) * 8 + ks * 32) * 2);
        o[df] = __builtin_amdgcn_mfma_f32_16x16x32_bf16(pa[ks], vf, o[df], 0, 0, 0);
      }
    __syncthreads();
  }

  // ---- epilogue: out = x + O / l ----
  float* ob = out + (((size_t)b * Tn + t) * Nn + n0) * Cn;
  float inv[4];
#pragma unroll
  for (int r = 0; r < 4; ++r) inv[r] = 1.0f / lrow[r];
#pragma unroll
  for (int df = 0; df < 8; ++df)
#pragma unroll
    for (int r = 0; r < 4; ++r) {
      int row = wv * 16 + (lane >> 4) * 4 + r;
      int col = df * 16 + (lane & 15);
      size_t idx = (size_t)row * Cn + col;
      ob[idx] = xb_g[idx] + o[df][r] * inv[r];
    }
#undef STAGE_X
#undef STAGE_WQ
}

extern "C" void kernel_launch(void* const* d_in, const int* in_sizes, int n_in,
                              void* d_out, int out_size, void* d_ws,
                              size_t ws_size, hipStream_t stream) {
  const float* x = (const float*)d_in[0];
  const float* rs = (const float*)d_in[1];
  const float* Wq = (const float*)d_in[2];
  const float* Wk = (const float*)d_in[3];
  const float* Wv = (const float*)d_in[4];
  float* out = (float*)d_out;

  // ws: K_hi [B][M][C] (2MB) | K_lo (2MB) | V^T [B][C][M] (2MB), all bf16
  unsigned short* kh_ws = (unsigned short*)d_ws;
  unsigned short* kl_ws = kh_ws + (size_t)Bn * Mn * Cn;
  unsigned short* vt_ws = kl_ws + (size_t)Bn * Mn * Cn;

  proj_kv_kernel<<<Bn * (Mn / 64), 256, 0, stream>>>(rs, Wk, Wv, kh_ws, kl_ws,
                                                     vt_ws);
  attn_kernel<<<Bn * Tn * (Nn / 128), 512, 0, stream>>>(x, Wq, kh_ws, kl_ws,
                                                        vt_ws, out);
}

// Round 3
// 273.343 us; speedup vs baseline: 1.0127x; 1.0127x over previous
//
#include <hip/hip_runtime.h>

// out = x + softmax((x@Wq) @ (rs@Wk)^T) @ (rs@Wv)
// B=4 T=8 N=2048 C=D=128 M=2048. fp32 in/out.
// hi/lo bf16 split (Markidis) for Q,K + 3-term QK^T; bf16 P,V.
// R3: 256 q-rows/block (32/wave), pre-swizzled tiled K/V in ws,
//     global_load_lds double-buffered staging, coalesced epilogue.

#define Bn 4
#define Tn 8
#define Nn 2048
#define Cn 128
#define Mn 2048
#define NTILES 32       // Mn/64
#define QROWS 256
#define NQT (Nn / QROWS)  // 8

typedef __attribute__((ext_vector_type(4))) float f32x4;
typedef __attribute__((ext_vector_type(8))) short bf16x8;
typedef __attribute__((address_space(3))) unsigned char lds_uc;
typedef const __attribute__((address_space(1))) unsigned char glb_uc;

__device__ __forceinline__ unsigned short f2bf(float f) {
  unsigned int u = __float_as_uint(f);
  u += 0x7fffu + ((u >> 16) & 1u);
  return (unsigned short)(u >> 16);
}
__device__ __forceinline__ float bf2f(unsigned short h) {
  return __uint_as_float(((unsigned int)h) << 16);
}
__device__ __forceinline__ unsigned short f2bf_lo(float v) {
  unsigned short h = f2bf(v);
  return f2bf(v - bf2f(h));
}
__device__ __forceinline__ bf16x8 lds_read8(const unsigned char* base, int row,
                                            int rowBytes, int colByte) {
  int byte = row * rowBytes + (colByte ^ ((row & 7) << 4));
  return *(const bf16x8*)(base + byte);
}
__device__ __forceinline__ void gld16(const void* g, void* l) {
  __builtin_amdgcn_global_load_lds((glb_uc*)g, (lds_uc*)l, 16, 0, 0);
}

// ---------------------------------------------------------------------------
// Kernel A: per (b, kt): K_hi/K_lo tile [64][128] and V^T tile [128][64],
// all bf16, PRE-SWIZZLED (byte ^= (row&7)<<4 within row), tile-contiguous:
//   kh_ws/kl_ws: [B][NTILES][64*128]   vt_ws: [B][NTILES][128*64]
// grid: B*NTILES = 128 blocks, 256 threads.
// ---------------------------------------------------------------------------
__global__ __launch_bounds__(256) void proj_kv_kernel(
    const float* __restrict__ rs, const float* __restrict__ Wk,
    const float* __restrict__ Wv, unsigned short* __restrict__ kh_ws,
    unsigned short* __restrict__ kl_ws, unsigned short* __restrict__ vt_ws) {
  __shared__ unsigned char smem[64 * 1024];
  unsigned char* rsh = smem;              // [64][128] bf16 swz
  unsigned char* rsl = smem + 16 * 1024;  // [64][128] bf16 swz
  unsigned char* wt = smem + 32 * 1024;   // [128][128] bf16 swz (W^T)

  const int bid = blockIdx.x;
  const int b = bid >> 5;
  const int kt = bid & 31;
  const int m0 = kt << 6;
  const int tid = threadIdx.x;
  const int wv = tid >> 6, lane = tid & 63;

  {
    const float4* g = (const float4*)(rs + ((size_t)b * Mn + m0) * Cn);
#pragma unroll
    for (int i = 0; i < 8; ++i) {
      int f = tid + i * 256;
      int row = f >> 5, c4 = f & 31;
      float4 v = g[f];
      int byte = row * 256 + ((c4 * 8) ^ ((row & 7) << 4));
      ushort4 h = make_ushort4(f2bf(v.x), f2bf(v.y), f2bf(v.z), f2bf(v.w));
      *(ushort4*)(rsh + byte) = h;
      *(ushort4*)(rsl + byte) =
          make_ushort4(f2bf(v.x - bf2f(h.x)), f2bf(v.y - bf2f(h.y)),
                       f2bf(v.z - bf2f(h.z)), f2bf(v.w - bf2f(h.w)));
    }
  }

#define STAGE_WT(Wp, LO)                                                      \
  {                                                                           \
    const float4* g = (const float4*)(Wp);                                    \
    _Pragma("unroll") for (int i = 0; i < 16; ++i) {                          \
      int f = tid + i * 256;                                                  \
      int c = f >> 5, d0 = (f & 31) * 4;                                      \
      float4 v = g[f];                                                        \
      float vv[4] = {v.x, v.y, v.z, v.w};                                     \
      _Pragma("unroll") for (int j = 0; j < 4; ++j) {                         \
        int row = d0 + j;                                                     \
        int byte = row * 256 + ((c * 2) ^ ((row & 7) << 4));                  \
        *(unsigned short*)(wt + byte) = (LO) ? f2bf_lo(vv[j]) : f2bf(vv[j]);  \
      }                                                                       \
    }                                                                         \
  }

  STAGE_WT(Wk, false);
  __syncthreads();

  const int arow = wv * 16 + (lane & 15);
  bf16x8 ah[4], al[4];
#pragma unroll
  for (int ks = 0; ks < 4; ++ks) {
    int cb = (lane >> 4) * 16 + ks * 64;
    ah[ks] = lds_read8(rsh, arow, 256, cb);
    al[ks] = lds_read8(rsl, arow, 256, cb);
  }

  f32x4 acc[8];
#pragma unroll
  for (int df = 0; df < 8; ++df) acc[df] = (f32x4)(0.0f);
#pragma unroll
  for (int ks = 0; ks < 4; ++ks)
#pragma unroll
    for (int df = 0; df < 8; ++df) {
      bf16x8 bf = lds_read8(wt, df * 16 + (lane & 15), 256,
                            (lane >> 4) * 16 + ks * 64);
      acc[df] = __builtin_amdgcn_mfma_f32_16x16x32_bf16(ah[ks], bf, acc[df], 0, 0, 0);
      acc[df] = __builtin_amdgcn_mfma_f32_16x16x32_bf16(al[ks], bf, acc[df], 0, 0, 0);
    }
  __syncthreads();
  STAGE_WT(Wk, true);
  __syncthreads();
#pragma unroll
  for (int ks = 0; ks < 4; ++ks)
#pragma unroll
    for (int df = 0; df < 8; ++df) {
      bf16x8 bf = lds_read8(wt, df * 16 + (lane & 15), 256,
                            (lane >> 4) * 16 + ks * 64);
      acc[df] = __builtin_amdgcn_mfma_f32_16x16x32_bf16(ah[ks], bf, acc[df], 0, 0, 0);
    }
  {
    unsigned char* khb = (unsigned char*)(kh_ws + ((size_t)b * NTILES + kt) * 8192);
    unsigned char* klb = (unsigned char*)(kl_ws + ((size_t)b * NTILES + kt) * 8192);
#pragma unroll
    for (int df = 0; df < 8; ++df)
#pragma unroll
      for (int r = 0; r < 4; ++r) {
        int row = wv * 16 + (lane >> 4) * 4 + r;   // tile-local m
        int dcol = df * 16 + (lane & 15);
        int byte = row * 256 + ((dcol * 2) ^ ((row & 7) << 4));
        float v = acc[df][r];
        unsigned short h = f2bf(v);
        *(unsigned short*)(khb + byte) = h;
        *(unsigned short*)(klb + byte) = f2bf(v - bf2f(h));
      }
  }
  __syncthreads();

  STAGE_WT(Wv, false);
  __syncthreads();
#pragma unroll
  for (int df = 0; df < 8; ++df) acc[df] = (f32x4)(0.0f);
#pragma unroll
  for (int ks = 0; ks < 4; ++ks)
#pragma unroll
    for (int df = 0; df < 8; ++df) {
      bf16x8 bf = lds_read8(wt, df * 16 + (lane & 15), 256,
                            (lane >> 4) * 16 + ks * 64);
      acc[df] = __builtin_amdgcn_mfma_f32_16x16x32_bf16(ah[ks], bf, acc[df], 0, 0, 0);
      acc[df] = __builtin_amdgcn_mfma_f32_16x16x32_bf16(al[ks], bf, acc[df], 0, 0, 0);
    }
  __syncthreads();
  STAGE_WT(Wv, true);
  __syncthreads();
#pragma unroll
  for (int ks = 0; ks < 4; ++ks)
#pragma unroll
    for (int df = 0; df < 8; ++df) {
      bf16x8 bf = lds_read8(wt, df * 16 + (lane & 15), 256,
                            (lane >> 4) * 16 + ks * 64);
      acc[df] = __builtin_amdgcn_mfma_f32_16x16x32_bf16(ah[ks], bf, acc[df], 0, 0, 0);
    }
  {
    unsigned char* vtb = (unsigned char*)(vt_ws + ((size_t)b * NTILES + kt) * 8192);
#pragma unroll
    for (int df = 0; df < 8; ++df)
#pragma unroll
      for (int r = 0; r < 4; ++r) {
        int row = wv * 16 + (lane >> 4) * 4 + r;   // tile-local m
        int dcol = df * 16 + (lane & 15);          // d (row of V^T tile)
        int byte = dcol * 128 + ((row * 2) ^ ((dcol & 7) << 4));
        *(unsigned short*)(vtb + byte) = f2bf(acc[df][r]);
      }
  }
#undef STAGE_WT
}

// ---------------------------------------------------------------------------
// Kernel B: fused flash attention. grid 256 blocks x 512 thr. LDS 128KB.
// Prologue: xa=[0,64K) x/q_hi [256][128]bf16, wqb=[64K,96K); q_lo later [64K,128K).
// Main: buf0=[0,48K), buf1=[48K,96K) {kh|kl|vt 16K each}, p=[96K)+wv*4K.
// Epilogue: per-wave O bounce at wv*16K.
// ---------------------------------------------------------------------------
__global__ __launch_bounds__(512, 2) void attn_kernel(
    const float* __restrict__ x, const float* __restrict__ Wq,
    const unsigned short* __restrict__ kh_ws,
    const unsigned short* __restrict__ kl_ws,
    const unsigned short* __restrict__ vt_ws, float* __restrict__ out) {
  __shared__ unsigned char smem[128 * 1024];

  const int bx = blockIdx.x;
  const int wb = ((bx & 7) << 5) | (bx >> 3);  // XCD swizzle (256 % 8 == 0)
  const int b = wb >> 6;                        // Tn*NQT = 64
  const int t = (wb >> 3) & 7;
  const int n0 = (wb & 7) * QROWS;
  const int tid = threadIdx.x;
  const int wv = tid >> 6, lane = tid & 63;

  const float* xg = x + (((size_t)b * Tn + t) * Nn + n0) * Cn;  // 256x128
  unsigned char* xa = smem;
  unsigned char* wqb = smem + 64 * 1024;
  unsigned char* pl = smem + 96 * 1024 + wv * 4096;  // per-wave P [32][64]

  // ---------------- prologue: q = x@Wq (3-term split) -------------------
  auto stage_x = [&](bool lo) {
    const float4* g = (const float4*)xg;
#pragma unroll
    for (int i = 0; i < 16; ++i) {
      int f = tid + i * 512;
      int row = f >> 5, c4 = f & 31;
      float4 v = g[f];
      int byte = row * 256 + ((c4 * 8) ^ ((row & 7) << 4));
      ushort4 w;
      if (lo)
        w = make_ushort4(f2bf_lo(v.x), f2bf_lo(v.y), f2bf_lo(v.z), f2bf_lo(v.w));
      else
        w = make_ushort4(f2bf(v.x), f2bf(v.y), f2bf(v.z), f2bf(v.w));
      *(ushort4*)(xa + byte) = w;
    }
  };
  auto stage_wq = [&](bool lo) {
    const float4* g = (const float4*)Wq;
#pragma unroll
    for (int i = 0; i < 8; ++i) {
      int f = tid + i * 512;
      int c = f >> 5, d0 = (f & 31) * 4;
      float4 v = g[f];
      float vv[4] = {v.x, v.y, v.z, v.w};
#pragma unroll
      for (int j = 0; j < 4; ++j) {
        int row = d0 + j;
        int byte = row * 256 + ((c * 2) ^ ((row & 7) << 4));
        *(unsigned short*)(wqb + byte) = lo ? f2bf_lo(vv[j]) : f2bf(vv[j]);
      }
    }
  };

  f32x4 qacc[2][8];
#pragma unroll
  for (int rb = 0; rb < 2; ++rb)
#pragma unroll
    for (int df = 0; df < 8; ++df) qacc[rb][df] = (f32x4)(0.0f);
  bf16x8 xf[2][4];
  auto read_xf = [&]() {
#pragma unroll
    for (int rb = 0; rb < 2; ++rb)
#pragma unroll
      for (int ks = 0; ks < 4; ++ks)
        xf[rb][ks] = lds_read8(xa, wv * 32 + rb * 16 + (lane & 15), 256,
                               (lane >> 4) * 16 + ks * 64);
  };
  auto qpass = [&]() {
#pragma unroll
    for (int ks = 0; ks < 4; ++ks)
#pragma unroll
      for (int df = 0; df < 8; ++df) {
        bf16x8 bf = lds_read8(wqb, df * 16 + (lane & 15), 256,
                              (lane >> 4) * 16 + ks * 64);
        qacc[0][df] = __builtin_amdgcn_mfma_f32_16x16x32_bf16(xf[0][ks], bf, qacc[0][df], 0, 0, 0);
        qacc[1][df] = __builtin_amdgcn_mfma_f32_16x16x32_bf16(xf[1][ks], bf, qacc[1][df], 0, 0, 0);
      }
  };

  stage_x(false);
  stage_wq(false);
  __syncthreads();
  read_xf();
  qpass();            // xh*wh
  __syncthreads();
  stage_wq(true);
  __syncthreads();
  qpass();            // xh*wl
  __syncthreads();
  stage_x(true);
  stage_wq(false);
  __syncthreads();
  read_xf();
  qpass();            // xl*wh
  __syncthreads();

  // split q -> hi/lo, round-trip to A-fragment layout (wave-local rows)
  unsigned char* qhb = smem;
  unsigned char* qlb = smem + 64 * 1024;
#pragma unroll
  for (int rb = 0; rb < 2; ++rb)
#pragma unroll
    for (int df = 0; df < 8; ++df)
#pragma unroll
      for (int r = 0; r < 4; ++r) {
        int row = wv * 32 + rb * 16 + (lane >> 4) * 4 + r;
        int col = df * 16 + (lane & 15);
        int byte = row * 256 + ((col * 2) ^ ((row & 7) << 4));
        float v = qacc[rb][df][r];
        unsigned short h = f2bf(v);
        *(unsigned short*)(qhb + byte) = h;
        *(unsigned short*)(qlb + byte) = f2bf(v - bf2f(h));
      }
  bf16x8 qh[2][4], ql[2][4];
#pragma unroll
  for (int rb = 0; rb < 2; ++rb)
#pragma unroll
    for (int ks = 0; ks < 4; ++ks) {
      int rw = wv * 32 + rb * 16 + (lane & 15);
      int cb = (lane >> 4) * 16 + ks * 64;
      qh[rb][ks] = lds_read8(qhb, rw, 256, cb);
      ql[rb][ks] = lds_read8(qlb, rw, 256, cb);
    }
  __syncthreads();

  // ---------------- main flash loop (double-buffered DMA) ----------------
  f32x4 o[2][8];
#pragma unroll
  for (int rb = 0; rb < 2; ++rb)
#pragma unroll
    for (int df = 0; df < 8; ++df) o[rb][df] = (f32x4)(0.0f);
  float mrow[2][4], lrow[2][4];
#pragma unroll
  for (int rb = 0; rb < 2; ++rb)
#pragma unroll
    for (int r = 0; r < 4; ++r) { mrow[rb][r] = -INFINITY; lrow[rb][r] = 0.f; }

  const unsigned char* khg = (const unsigned char*)(kh_ws + (size_t)b * NTILES * 8192);
  const unsigned char* klg = (const unsigned char*)(kl_ws + (size_t)b * NTILES * 8192);
  const unsigned char* vtg = (const unsigned char*)(vt_ws + (size_t)b * NTILES * 8192);

  auto stage = [&](unsigned char* buf, int kt) {
    const unsigned char* kh = khg + (size_t)kt * 16384;
    const unsigned char* kl = klg + (size_t)kt * 16384;
    const unsigned char* vt = vtg + (size_t)kt * 16384;
    int o16 = tid * 16;
    gld16(kh + o16, buf + o16);
    gld16(kh + o16 + 8192, buf + o16 + 8192);
    gld16(kl + o16, buf + 16384 + o16);
    gld16(kl + o16 + 8192, buf + 16384 + o16 + 8192);
    gld16(vt + o16, buf + 32768 + o16);
    gld16(vt + o16 + 8192, buf + 32768 + o16 + 8192);
  };

  auto do_tile = [&](unsigned char* buf) {
    unsigned char* kh = buf;
    unsigned char* kl = buf + 16384;
    unsigned char* vt = buf + 32768;
    f32x4 s[2][4];
#pragma unroll
    for (int rb = 0; rb < 2; ++rb)
#pragma unroll
      for (int jf = 0; jf < 4; ++jf) s[rb][jf] = (f32x4)(0.0f);
#pragma unroll
    for (int ks = 0; ks < 4; ++ks)
#pragma unroll
      for (int jf = 0; jf < 4; ++jf) {
        int cb = (lane >> 4) * 16 + ks * 64;
        bf16x8 kfh = lds_read8(kh, jf * 16 + (lane & 15), 256, cb);
        bf16x8 kfl = lds_read8(kl, jf * 16 + (lane & 15), 256, cb);
        s[0][jf] = __builtin_amdgcn_mfma_f32_16x16x32_bf16(qh[0][ks], kfh, s[0][jf], 0, 0, 0);
        s[1][jf] = __builtin_amdgcn_mfma_f32_16x16x32_bf16(qh[1][ks], kfh, s[1][jf], 0, 0, 0);
        s[0][jf] = __builtin_amdgcn_mfma_f32_16x16x32_bf16(ql[0][ks], kfh, s[0][jf], 0, 0, 0);
        s[1][jf] = __builtin_amdgcn_mfma_f32_16x16x32_bf16(ql[1][ks], kfh, s[1][jf], 0, 0, 0);
        s[0][jf] = __builtin_amdgcn_mfma_f32_16x16x32_bf16(qh[0][ks], kfl, s[0][jf], 0, 0, 0);
        s[1][jf] = __builtin_amdgcn_mfma_f32_16x16x32_bf16(qh[1][ks], kfl, s[1][jf], 0, 0, 0);
      }

#pragma unroll
    for (int rb = 0; rb < 2; ++rb) {
      float scl[4];
#pragma unroll
      for (int r = 0; r < 4; ++r) {
        float tm = fmaxf(fmaxf(s[rb][0][r], s[rb][1][r]),
                         fmaxf(s[rb][2][r], s[rb][3][r]));
#pragma unroll
        for (int off = 1; off < 16; off <<= 1)
          tm = fmaxf(tm, __shfl_xor(tm, off, 16));
        float mn = fmaxf(mrow[rb][r], tm);
        scl[r] = __expf(mrow[rb][r] - mn);
        float rsum = 0.f;
#pragma unroll
        for (int jf = 0; jf < 4; ++jf) {
          float p = __expf(s[rb][jf][r] - mn);
          s[rb][jf][r] = p;
          rsum += p;
        }
#pragma unroll
        for (int off = 1; off < 16; off <<= 1) rsum += __shfl_xor(rsum, off, 16);
        lrow[rb][r] = lrow[rb][r] * scl[r] + rsum;
        mrow[rb][r] = mn;
      }
#pragma unroll
      for (int df = 0; df < 8; ++df)
#pragma unroll
        for (int r = 0; r < 4; ++r) o[rb][df][r] *= scl[r];
#pragma unroll
      for (int jf = 0; jf < 4; ++jf)
#pragma unroll
        for (int r = 0; r < 4; ++r) {
          int prow = rb * 16 + (lane >> 4) * 4 + r;
          int byte = prow * 128 + (((jf * 16 + (lane & 15)) * 2) ^ ((prow & 7) << 4));
          *(unsigned short*)(pl + byte) = f2bf(s[rb][jf][r]);
        }
    }
    bf16x8 pa[2][2];
#pragma unroll
    for (int rb = 0; rb < 2; ++rb)
#pragma unroll
      for (int ks = 0; ks < 2; ++ks)
        pa[rb][ks] = lds_read8(pl, rb * 16 + (lane & 15), 128,
                               (lane >> 4) * 16 + ks * 64);
#pragma unroll
    for (int ks = 0; ks < 2; ++ks)
#pragma unroll
      for (int df = 0; df < 8; ++df) {
        bf16x8 vf = lds_read8(vt, df * 16 + (lane & 15), 128,
                              (lane >> 4) * 16 + ks * 64);
        o[0][df] = __builtin_amdgcn_mfma_f32_16x16x32_bf16(pa[0][ks], vf, o[0][df], 0, 0, 0);
        o[1][df] = __builtin_amdgcn_mfma_f32_16x16x32_bf16(pa[1][ks], vf, o[1][df], 0, 0, 0);
      }
  };

  unsigned char* B0 = smem;
  unsigned char* B1 = smem + 48 * 1024;
  stage(B0, 0);
  __syncthreads();
#pragma unroll 1
  for (int it = 0; it < 16; ++it) {
    int kt = it * 2;
    stage(B1, kt + 1);
    do_tile(B0);
    __syncthreads();
    if (kt + 2 < NTILES) stage(B0, kt + 2);
    do_tile(B1);
    __syncthreads();
  }

  // ---------------- epilogue: out = x + O/l (coalesced) ------------------
#pragma unroll
  for (int rb = 0; rb < 2; ++rb) {
    float inv[4];
#pragma unroll
    for (int r = 0; r < 4; ++r) inv[r] = 1.0f / lrow[rb][r];
#pragma unroll
    for (int df = 0; df < 8; ++df)
#pragma unroll
      for (int r = 0; r < 4; ++r) o[rb][df][r] *= inv[r];
  }
  unsigned char* ow = smem + wv * 16384;  // [32][128] f32, swizzled
#pragma unroll
  for (int rb = 0; rb < 2; ++rb)
#pragma unroll
    for (int df = 0; df < 8; ++df)
#pragma unroll
      for (int r = 0; r < 4; ++r) {
        int row = rb * 16 + (lane >> 4) * 4 + r;
        int col = df * 16 + (lane & 15);
        int byte = row * 512 + ((col * 4) ^ ((row & 7) << 4));
        *(float*)(ow + byte) = o[rb][df][r];
      }
  const float4* xg4 = (const float4*)(xg + (size_t)wv * 32 * Cn);
  float4* og4 = (float4*)(out + (((size_t)b * Tn + t) * Nn + n0 + wv * 32) * Cn);
#pragma unroll
  for (int i = 0; i < 16; ++i) {
    int f = lane + i * 64;
    int row = f >> 5, c4 = f & 31;
    int byte = row * 512 + ((c4 * 16) ^ ((row & 7) << 4));
    f32x4 v = *(const f32x4*)(ow + byte);
    float4 xv = xg4[f];
    og4[f] = make_float4(xv.x + v[0], xv.y + v[1], xv.z + v[2], xv.w + v[3]);
  }
}

extern "C" void kernel_launch(void* const* d_in, const int* in_sizes, int n_in,
                              void* d_out, int out_size, void* d_ws,
                              size_t ws_size, hipStream_t stream) {
  const float* x = (const float*)d_in[0];
  const float* rs = (const float*)d_in[1];
  const float* Wq = (const float*)d_in[2];
  const float* Wk = (const float*)d_in[3];
  const float* Wv = (const float*)d_in[4];
  float* out = (float*)d_out;

  unsigned short* kh_ws = (unsigned short*)d_ws;
  unsigned short* kl_ws = kh_ws + (size_t)Bn * Mn * Cn;
  unsigned short* vt_ws = kl_ws + (size_t)Bn * Mn * Cn;

  proj_kv_kernel<<<Bn * NTILES, 256, 0, stream>>>(rs, Wk, Wv, kh_ws, kl_ws, vt_ws);
  attn_kernel<<<Bn * Tn * NQT, 512, 0, stream>>>(x, Wq, kh_ws, kl_ws, vt_ws, out);
}

// Round 4
// 122.544 us; speedup vs baseline: 2.2589x; 2.2306x over previous
//
#include <hip/hip_runtime.h>

// out = x + softmax((x@Wq) @ (rs@Wk)^T) @ (rs@Wv)
// B=4 T=8 N=2048 C=D=128 M=2048. fp32 in/out, fp16 MFMA compute (f32 accum).
// R4: transposed dataflow (S^T,P^T,O^T) -> lane-local softmax (2 shuffles),
//     fp16 single-pass (no hi/lo split), 2 blocks/CU.

#define Bn 4
#define Tn 8
#define Nn 2048
#define Cn 128
#define Mn 2048
#define NTILES 32        // Mn/64
#define QROWS 128
#define NQT (Nn / QROWS) // 16

typedef __attribute__((ext_vector_type(4))) float f32x4;
typedef __attribute__((ext_vector_type(8))) _Float16 f16x8;
typedef __attribute__((address_space(3))) unsigned char lds_uc;
typedef const __attribute__((address_space(1))) unsigned char glb_uc;

__device__ __forceinline__ unsigned short f2h(float f) {
  _Float16 h = (_Float16)f;
  return __builtin_bit_cast(unsigned short, h);
}
// Swizzled LDS read of 8 f16 (16B). byte ^= (row&7)<<4 (bank-conflict fix).
__device__ __forceinline__ f16x8 lds_read8(const unsigned char* base, int row,
                                           int rowBytes, int colByte) {
  int byte = row * rowBytes + (colByte ^ ((row & 7) << 4));
  return *(const f16x8*)(base + byte);
}
__device__ __forceinline__ void gld16(const void* g, void* l) {
  __builtin_amdgcn_global_load_lds((glb_uc*)g, (lds_uc*)l, 16, 0, 0);
}

// ---------------------------------------------------------------------------
// Kernel A: per (b,kt): K tile [64 m][128 d] f16 and V^T tile [128 d][64 m]
// f16, PRE-SWIZZLED, tile-contiguous: k_ws/vt_ws: [B][NTILES][8192] f16.
// grid: B*NTILES = 128 blocks, 256 threads. LDS 48KB.
// ---------------------------------------------------------------------------
__global__ __launch_bounds__(256) void proj_kv_kernel(
    const float* __restrict__ rs, const float* __restrict__ Wk,
    const float* __restrict__ Wv, unsigned short* __restrict__ k_ws,
    unsigned short* __restrict__ vt_ws) {
  __shared__ unsigned char smem[48 * 1024];
  unsigned char* rsh = smem;             // [64][128] f16 swz (16KB)
  unsigned char* wt = smem + 16 * 1024;  // [128][128] f16 swz, W^T (32KB)

  const int bid = blockIdx.x;
  const int b = bid >> 5;
  const int kt = bid & 31;
  const int m0 = kt << 6;
  const int tid = threadIdx.x;
  const int wv = tid >> 6, lane = tid & 63;

  {
    const float4* g = (const float4*)(rs + ((size_t)b * Mn + m0) * Cn);
#pragma unroll
    for (int i = 0; i < 8; ++i) {
      int f = tid + i * 256;
      int row = f >> 5, c4 = f & 31;
      float4 v = g[f];
      int byte = row * 256 + ((c4 * 8) ^ ((row & 7) << 4));
      *(ushort4*)(rsh + byte) =
          make_ushort4(f2h(v.x), f2h(v.y), f2h(v.z), f2h(v.w));
    }
  }

#define STAGE_WT(Wp)                                                          \
  {                                                                           \
    const float4* g = (const float4*)(Wp);                                    \
    _Pragma("unroll") for (int i = 0; i < 16; ++i) {                          \
      int f = tid + i * 256;                                                  \
      int c = f >> 5, d0 = (f & 31) * 4;                                      \
      float4 v = g[f];                                                        \
      float vv[4] = {v.x, v.y, v.z, v.w};                                     \
      _Pragma("unroll") for (int j = 0; j < 4; ++j) {                         \
        int row = d0 + j;                                                     \
        int byte = row * 256 + ((c * 2) ^ ((row & 7) << 4));                  \
        *(unsigned short*)(wt + byte) = f2h(vv[j]);                           \
      }                                                                       \
    }                                                                         \
  }

  STAGE_WT(Wk);
  __syncthreads();

  const int arow = wv * 16 + (lane & 15);
  f16x8 ah[4];
#pragma unroll
  for (int ks = 0; ks < 4; ++ks)
    ah[ks] = lds_read8(rsh, arow, 256, (lane >> 4) * 16 + ks * 64);

  f32x4 acc[8];
#pragma unroll
  for (int df = 0; df < 8; ++df) acc[df] = (f32x4)(0.0f);
#pragma unroll
  for (int ks = 0; ks < 4; ++ks)
#pragma unroll
    for (int df = 0; df < 8; ++df) {
      f16x8 bf = lds_read8(wt, df * 16 + (lane & 15), 256,
                           (lane >> 4) * 16 + ks * 64);
      acc[df] = __builtin_amdgcn_mfma_f32_16x16x32_f16(ah[ks], bf, acc[df], 0, 0, 0);
    }
  {
    unsigned char* kb = (unsigned char*)(k_ws + ((size_t)b * NTILES + kt) * 8192);
#pragma unroll
    for (int df = 0; df < 8; ++df)
#pragma unroll
      for (int r = 0; r < 4; ++r) {
        int row = wv * 16 + (lane >> 4) * 4 + r;   // tile-local m
        int dcol = df * 16 + (lane & 15);
        int byte = row * 256 + ((dcol * 2) ^ ((row & 7) << 4));
        *(unsigned short*)(kb + byte) = f2h(acc[df][r]);
      }
  }
  __syncthreads();

  STAGE_WT(Wv);
  __syncthreads();
#pragma unroll
  for (int df = 0; df < 8; ++df) acc[df] = (f32x4)(0.0f);
#pragma unroll
  for (int ks = 0; ks < 4; ++ks)
#pragma unroll
    for (int df = 0; df < 8; ++df) {
      f16x8 bf = lds_read8(wt, df * 16 + (lane & 15), 256,
                           (lane >> 4) * 16 + ks * 64);
      acc[df] = __builtin_amdgcn_mfma_f32_16x16x32_f16(ah[ks], bf, acc[df], 0, 0, 0);
    }
  {
    unsigned char* vb = (unsigned char*)(vt_ws + ((size_t)b * NTILES + kt) * 8192);
#pragma unroll
    for (int df = 0; df < 8; ++df)
#pragma unroll
      for (int r = 0; r < 4; ++r) {
        int row = wv * 16 + (lane >> 4) * 4 + r;   // tile-local m
        int dcol = df * 16 + (lane & 15);          // d (row of V^T tile)
        int byte = dcol * 128 + ((row * 2) ^ ((dcol & 7) << 4));
        *(unsigned short*)(vb + byte) = f2h(acc[df][r]);
      }
  }
#undef STAGE_WT
}

// ---------------------------------------------------------------------------
// Kernel B: fused flash attention, transposed dataflow.
// grid B*T*NQT = 512 blocks, 256 thr (4 waves x 32 q-rows). LDS 80KB:
//  prologue: xa[128][128]f16 @0 (32K), wq^T @32K (32K)
//  main: B0@0 {K 16K | Vt 16K}, B1@32K, P @64K + wv*4K ([2 rb][16 q][64 kv])
//  epilogue: O^T bounce @0 (64K)
// Per wave: S^T = mfma(K, Q) -> lane owns q-row (col=lane&15) -> in-reg
// softmax (2 shuffles); O^T = mfma(V^T, P) -> same lane-q layout.
// ---------------------------------------------------------------------------
__global__ __launch_bounds__(256, 2) void attn_kernel(
    const float* __restrict__ x, const float* __restrict__ Wq,
    const unsigned short* __restrict__ k_ws,
    const unsigned short* __restrict__ vt_ws, float* __restrict__ out) {
  __shared__ unsigned char smem[80 * 1024];

  const int bx = blockIdx.x;
  const int wb = ((bx & 7) << 6) | (bx >> 3);  // XCD swizzle (512 % 8 == 0)
  const int b = wb >> 7;                        // Tn*NQT = 128 per batch
  const int t = (wb >> 4) & 7;
  const int n0 = (wb & 15) * QROWS;
  const int tid = threadIdx.x;
  const int wv = tid >> 6, lane = tid & 63;

  const float* xg = x + (((size_t)b * Tn + t) * Nn + n0) * Cn;  // 128x128
  unsigned char* xa = smem;
  unsigned char* wqb = smem + 32 * 1024;
  unsigned char* pb = smem + 64 * 1024 + wv * 4096;

  // ---- prologue: q = x@Wq (f16), kept as fragments in regs ----
  {
    const float4* g = (const float4*)xg;
#pragma unroll
    for (int i = 0; i < 16; ++i) {
      int f = tid + i * 256;
      int row = f >> 5, c4 = f & 31;
      float4 v = g[f];
      int byte = row * 256 + ((c4 * 8) ^ ((row & 7) << 4));
      *(ushort4*)(xa + byte) =
          make_ushort4(f2h(v.x), f2h(v.y), f2h(v.z), f2h(v.w));
    }
  }
  {
    const float4* g = (const float4*)Wq;
#pragma unroll
    for (int i = 0; i < 16; ++i) {
      int f = tid + i * 256;
      int c = f >> 5, d0 = (f & 31) * 4;
      float4 v = g[f];
      float vv[4] = {v.x, v.y, v.z, v.w};
#pragma unroll
      for (int j = 0; j < 4; ++j) {
        int row = d0 + j;
        int byte = row * 256 + ((c * 2) ^ ((row & 7) << 4));
        *(unsigned short*)(wqb + byte) = f2h(vv[j]);
      }
    }
  }
  __syncthreads();

  f32x4 qacc[2][8];
#pragma unroll
  for (int rb = 0; rb < 2; ++rb)
#pragma unroll
    for (int df = 0; df < 8; ++df) qacc[rb][df] = (f32x4)(0.0f);
  {
    f16x8 xf[2][4];
#pragma unroll
    for (int rb = 0; rb < 2; ++rb)
#pragma unroll
      for (int ks = 0; ks < 4; ++ks)
        xf[rb][ks] = lds_read8(xa, wv * 32 + rb * 16 + (lane & 15), 256,
                               (lane >> 4) * 16 + ks * 64);
#pragma unroll
    for (int ks = 0; ks < 4; ++ks)
#pragma unroll
      for (int df = 0; df < 8; ++df) {
        f16x8 bf = lds_read8(wqb, df * 16 + (lane & 15), 256,
                             (lane >> 4) * 16 + ks * 64);
        qacc[0][df] = __builtin_amdgcn_mfma_f32_16x16x32_f16(xf[0][ks], bf, qacc[0][df], 0, 0, 0);
        qacc[1][df] = __builtin_amdgcn_mfma_f32_16x16x32_f16(xf[1][ks], bf, qacc[1][df], 0, 0, 0);
      }
  }
  // write q (f16) into own rows of xa, re-read as fragments (wave-local)
#pragma unroll
  for (int rb = 0; rb < 2; ++rb)
#pragma unroll
    for (int df = 0; df < 8; ++df)
#pragma unroll
      for (int r = 0; r < 4; ++r) {
        int row = wv * 32 + rb * 16 + (lane >> 4) * 4 + r;
        int col = df * 16 + (lane & 15);
        int byte = row * 256 + ((col * 2) ^ ((row & 7) << 4));
        *(unsigned short*)(xa + byte) = f2h(qacc[rb][df][r]);
      }
  f16x8 qf[2][4];
#pragma unroll
  for (int rb = 0; rb < 2; ++rb)
#pragma unroll
    for (int ks = 0; ks < 4; ++ks)
      qf[rb][ks] = lds_read8(xa, wv * 32 + rb * 16 + (lane & 15), 256,
                             (lane >> 4) * 16 + ks * 64);
  __syncthreads();

  // ---- main flash loop ----
  f32x4 o[2][8];  // O^T fragments: col=lane&15 = q-row, rows = d
#pragma unroll
  for (int rb = 0; rb < 2; ++rb)
#pragma unroll
    for (int df = 0; df < 8; ++df) o[rb][df] = (f32x4)(0.0f);
  float mrow[2] = {-INFINITY, -INFINITY};
  float lrow[2] = {0.f, 0.f};

  const unsigned char* khg = (const unsigned char*)(k_ws + (size_t)b * NTILES * 8192);
  const unsigned char* vtg = (const unsigned char*)(vt_ws + (size_t)b * NTILES * 8192);

  auto stage = [&](unsigned char* buf, int kt) {
    const unsigned char* kh = khg + (size_t)kt * 16384;
    const unsigned char* vt = vtg + (size_t)kt * 16384;
    int o16 = tid * 16;  // 256 thr x 16B = 4KB per call
#pragma unroll
    for (int h = 0; h < 4; ++h) {
      gld16(kh + o16 + h * 4096, buf + o16 + h * 4096);
      gld16(vt + o16 + h * 4096, buf + 16384 + o16 + h * 4096);
    }
  };

  auto do_tile = [&](unsigned char* buf) {
    unsigned char* kh = buf;
    unsigned char* vt = buf + 16384;
    // S^T[kv][q] = K @ Q : A=K rows(kv), B=Q cols(q)
    f32x4 st[2][4];
#pragma unroll
    for (int rb = 0; rb < 2; ++rb)
#pragma unroll
      for (int kvb = 0; kvb < 4; ++kvb) st[rb][kvb] = (f32x4)(0.0f);
    __builtin_amdgcn_s_setprio(1);
#pragma unroll
    for (int ks = 0; ks < 4; ++ks)
#pragma unroll
      for (int kvb = 0; kvb < 4; ++kvb) {
        f16x8 kf = lds_read8(kh, kvb * 16 + (lane & 15), 256,
                             (lane >> 4) * 16 + ks * 64);
        st[0][kvb] = __builtin_amdgcn_mfma_f32_16x16x32_f16(kf, qf[0][ks], st[0][kvb], 0, 0, 0);
        st[1][kvb] = __builtin_amdgcn_mfma_f32_16x16x32_f16(kf, qf[1][ks], st[1][kvb], 0, 0, 0);
      }
    __builtin_amdgcn_s_setprio(0);

    // online softmax: lane owns q-row (q = lane&15); kv values in regs
#pragma unroll
    for (int rb = 0; rb < 2; ++rb) {
      float tm = st[rb][0][0];
#pragma unroll
      for (int kvb = 0; kvb < 4; ++kvb)
#pragma unroll
        for (int r = 0; r < 4; ++r) tm = fmaxf(tm, st[rb][kvb][r]);
      tm = fmaxf(tm, __shfl_xor(tm, 16));
      tm = fmaxf(tm, __shfl_xor(tm, 32));
      float mn = fmaxf(mrow[rb], tm);
      float scl = __expf(mrow[rb] - mn);
      float rsum = 0.f;
#pragma unroll
      for (int kvb = 0; kvb < 4; ++kvb)
#pragma unroll
        for (int r = 0; r < 4; ++r) {
          float p = __expf(st[rb][kvb][r] - mn);
          st[rb][kvb][r] = p;
          rsum += p;
        }
      rsum += __shfl_xor(rsum, 16);
      rsum += __shfl_xor(rsum, 32);
      lrow[rb] = lrow[rb] * scl + rsum;
      mrow[rb] = mn;
#pragma unroll
      for (int df = 0; df < 8; ++df) o[rb][df] *= scl;
      // write P[q][kv] (f16, swizzled) - per-wave buffer, in-wave ordering
#pragma unroll
      for (int kvb = 0; kvb < 4; ++kvb)
#pragma unroll
        for (int r = 0; r < 4; ++r) {
          int kv = kvb * 16 + (lane >> 4) * 4 + r;
          int byte = (lane & 15) * 128 + ((kv * 2) ^ ((lane & 7) << 4));
          *(unsigned short*)(pb + rb * 2048 + byte) = f2h(st[rb][kvb][r]);
        }
    }
    f16x8 pa[2][2];
#pragma unroll
    for (int rb = 0; rb < 2; ++rb)
#pragma unroll
      for (int ks = 0; ks < 2; ++ks)
        pa[rb][ks] = lds_read8(pb + rb * 2048, lane & 15, 128,
                               (lane >> 4) * 16 + ks * 64);
    // O^T += V^T @ P : A=V^T rows(d), B=P cols(q)
    __builtin_amdgcn_s_setprio(1);
#pragma unroll
    for (int ks = 0; ks < 2; ++ks)
#pragma unroll
      for (int df = 0; df < 8; ++df) {
        f16x8 vf = lds_read8(vt, df * 16 + (lane & 15), 128,
                             (lane >> 4) * 16 + ks * 64);
        o[0][df] = __builtin_amdgcn_mfma_f32_16x16x32_f16(vf, pa[0][ks], o[0][df], 0, 0, 0);
        o[1][df] = __builtin_amdgcn_mfma_f32_16x16x32_f16(vf, pa[1][ks], o[1][df], 0, 0, 0);
      }
    __builtin_amdgcn_s_setprio(0);
  };

  unsigned char* B0 = smem;
  unsigned char* B1 = smem + 32 * 1024;
  stage(B0, 0);
  __syncthreads();
#pragma unroll 1
  for (int it = 0; it < 16; ++it) {
    int kt = it * 2;
    stage(B1, kt + 1);
    do_tile(B0);
    __syncthreads();
    if (kt + 2 < NTILES) stage(B0, kt + 2);
    do_tile(B1);
    __syncthreads();
  }

  // ---- epilogue: out = x + O/l (O^T bounce through LDS, coalesced out) ----
  float inv[2] = {1.0f / lrow[0], 1.0f / lrow[1]};
#pragma unroll
  for (int rb = 0; rb < 2; ++rb)
#pragma unroll
    for (int df = 0; df < 8; ++df)
#pragma unroll
      for (int r = 0; r < 4; ++r) {
        int row = wv * 32 + rb * 16 + (lane & 15);     // q-row (block-local)
        int d = df * 16 + (lane >> 4) * 4 + r;
        int byte = row * 512 + ((d * 4) ^ ((row & 7) << 4));
        *(float*)(smem + byte) = o[rb][df][r] * inv[rb];
      }
  __syncthreads();
  {
    const float4* xg4 = (const float4*)xg;
    float4* og4 = (float4*)(out + (((size_t)b * Tn + t) * Nn + n0) * Cn);
#pragma unroll
    for (int i = 0; i < 16; ++i) {
      int f = tid + i * 256;
      int row = f >> 5, c4 = f & 31;
      int byte = row * 512 + ((c4 * 16) ^ ((row & 7) << 4));
      f32x4 v = *(const f32x4*)(smem + byte);
      float4 xv = xg4[f];
      og4[f] = make_float4(xv.x + v[0], xv.y + v[1], xv.z + v[2], xv.w + v[3]);
    }
  }
}

extern "C" void kernel_launch(void* const* d_in, const int* in_sizes, int n_in,
                              void* d_out, int out_size, void* d_ws,
                              size_t ws_size, hipStream_t stream) {
  const float* x = (const float*)d_in[0];
  const float* rs = (const float*)d_in[1];
  const float* Wq = (const float*)d_in[2];
  const float* Wk = (const float*)d_in[3];
  const float* Wv = (const float*)d_in[4];
  float* out = (float*)d_out;

  // ws: K f16 tiles [B][32][8192] (2MB) | V^T f16 tiles [B][32][8192] (2MB)
  unsigned short* k_ws = (unsigned short*)d_ws;
  unsigned short* vt_ws = k_ws + (size_t)Bn * Mn * Cn;

  proj_kv_kernel<<<Bn * NTILES, 256, 0, stream>>>(rs, Wk, Wv, k_ws, vt_ws);
  attn_kernel<<<Bn * Tn * NQT, 256, 0, stream>>>(x, Wq, k_ws, vt_ws, out);
}